// Round 1
// baseline (3619.406 us; speedup 1.0000x reference)
//
#include <hip/hip_runtime.h>

typedef unsigned short u16;
typedef __attribute__((ext_vector_type(8))) short bf16x8;
typedef __attribute__((ext_vector_type(4))) float f32x4;
typedef __attribute__((ext_vector_type(4))) unsigned short us4;

#define MFMA(a,b,c) __builtin_amdgcn_mfma_f32_16x16x32_bf16((a),(b),(c),0,0,0)

// B=128, SEQ=200, VOCAB=1400 (pad 1408), D=H=256, 4H=1024, NCLS=128, M=B*SEQ=25600

static __device__ __forceinline__ u16 f2b(float f){
  unsigned u = __float_as_uint(f);
  u += 0x7fffu + ((u >> 16) & 1u);          // RNE fp32 -> bf16
  return (u16)(u >> 16);
}
static __device__ __forceinline__ float sigm(float x){ return 1.0f/(1.0f+__expf(-x)); }
static __device__ __forceinline__ float tanhx(float x){
  x = fminf(fmaxf(x, -15.f), 15.f);
  float e = __expf(-2.f*x);
  return (1.f - e)/(1.f + e);
}
static __device__ __forceinline__ void gl16(const void* g, void* l){
  __builtin_amdgcn_global_load_lds((const __attribute__((address_space(1))) void*)g,
                                   (__attribute__((address_space(3))) void*)l, 16, 0, 0);
}

// ---------------- fp32 -> bf16 convert (+ zero column pad) ----------------
__global__ __launch_bounds__(256) void k_cvt4(const float* __restrict__ src, u16* __restrict__ dst,
                                              int cin, int cout, long long tot4){
  long long i4 = (long long)blockIdx.x*256 + threadIdx.x;
  if (i4 >= tot4) return;
  long long o = i4*4;
  int r = (int)(o / cout);
  int c = (int)(o % cout);
  us4 d;
  if (c + 4 <= cin){
    f32x4 v = *(const f32x4*)&src[(long long)r*cin + c];
    d[0]=f2b(v[0]); d[1]=f2b(v[1]); d[2]=f2b(v[2]); d[3]=f2b(v[3]);
  } else {
    for (int k=0;k<4;k++){ int cc=c+k; d[k] = (cc<cin)? f2b(src[(long long)r*cin+cc]) : (u16)0; }
  }
  *(us4*)&dst[(long long)r*cout + c] = d;
}

// emb [K=1400][N=256] -> dst [N=256][Kp=1408] bf16 (transposed, padded)
__global__ __launch_bounds__(256) void k_tcvt(const float* __restrict__ src, u16* __restrict__ dst,
                                              int K, int N, int Kp){
  int idx = blockIdx.x*256 + threadIdx.x;
  if (idx >= N*Kp) return;
  int n = idx / Kp, k = idx % Kp;
  dst[idx] = (k < K) ? f2b(src[(long long)k*N + n]) : (u16)0;
}

// ---------------- bf16 MFMA GEMM: C[M,N] = A[M,K] * Bt[N,K]^T -------------
// EPI: 1 = write fp32 + bf16 copies; 2 = +bias1[col]+bias2[col], fp32;
//      3 = P = emb[row,col] * tanh(acc) * alpha[row], fp32
template<int EPI>
__global__ __launch_bounds__(256) void k_gemm(const u16* __restrict__ A, const u16* __restrict__ Bt,
    int N, int K,
    float* __restrict__ Cf, u16* __restrict__ Cb,
    const float* __restrict__ bias1, const float* __restrict__ bias2,
    const float* __restrict__ emb, const float* __restrict__ alpha)
{
  __shared__ __align__(16) u16 As[128*64];
  __shared__ __align__(16) u16 Bs[128*64];
  const int tid = threadIdx.x;
  const int l = tid & 63, w = tid >> 6;
  const int quad = l >> 4, lb = l & 15;
  const int wr = w >> 1, wc = w & 1;
  const long long m0 = (long long)blockIdx.x * 128;
  const int n0 = blockIdx.y * 128;

  f32x4 acc[4][4];
  #pragma unroll
  for (int i=0;i<4;i++)
    #pragma unroll
    for (int j=0;j<4;j++) acc[i][j] = (f32x4){0.f,0.f,0.f,0.f};

  for (int kk = 0; kk < K; kk += 64){
    #pragma unroll
    for (int it=0; it<4; ++it){      // 128x64 bf16 tile, XOR-swizzled 16B slots
      int slot = it*256 + tid;
      int m = slot >> 3;
      int q = (slot & 7) ^ (m & 7);
      gl16(A + (m0+m)*K + kk + q*8, &As[slot*8]);
    }
    #pragma unroll
    for (int it=0; it<4; ++it){
      int slot = it*256 + tid;
      int m = slot >> 3;
      int q = (slot & 7) ^ (m & 7);
      gl16(Bt + (long long)(n0+m)*K + kk + q*8, &Bs[slot*8]);
    }
    __syncthreads();
    #pragma unroll
    for (int ks=0; ks<2; ++ks){
      int kq = quad + ks*4;
      bf16x8 af[4], bfr[4];
      #pragma unroll
      for (int i=0;i<4;i++){ int m = wr*64 + i*16 + lb; af[i]  = *(const bf16x8*)&As[m*64 + ((kq ^ (m&7))*8)]; }
      #pragma unroll
      for (int j=0;j<4;j++){ int n = wc*64 + j*16 + lb; bfr[j] = *(const bf16x8*)&Bs[n*64 + ((kq ^ (n&7))*8)]; }
      #pragma unroll
      for (int i=0;i<4;i++)
        #pragma unroll
        for (int j=0;j<4;j++)
          acc[i][j] = MFMA(af[i], bfr[j], acc[i][j]);
    }
    __syncthreads();
  }
  #pragma unroll
  for (int i=0;i<4;i++){
    #pragma unroll
    for (int j=0;j<4;j++){
      int col = n0 + wc*64 + j*16 + lb;
      #pragma unroll
      for (int r=0;r<4;r++){
        long long row = m0 + wr*64 + i*16 + quad*4 + r;
        long long o = row*N + col;
        float v = acc[i][j][r];
        if (EPI==1){ Cf[o]=v; Cb[o]=f2b(v); }
        else if (EPI==2){ Cf[o] = v + bias1[col] + bias2[col]; }
        else if (EPI==3){ Cf[o] = emb[o] * tanhx(v) * alpha[row]; }
        else { Cf[o]=v; }
      }
    }
  }
}

// ---------------- persistent TimeLSTM scan ----------------
// 16 WGs: blockIdx>>3 = lstm id, blockIdx&7 = batch chunk of 16.
// h,c live in registers in MFMA C-layout (row=j, col=batch); LDS holds bf16
// h/c as B-operand [batch][k]; Wall/Wd stream from L2 as A-fragments.
__global__ __launch_bounds__(256) void k_scan(
  const u16* __restrict__ WallA, const u16* __restrict__ WdA, const float* __restrict__ WdbA,
  const float* __restrict__ uxA, const float* __restrict__ h0A, const float* __restrict__ c0A,
  float* __restrict__ out1,
  const u16* __restrict__ WallB, const u16* __restrict__ WdB, const float* __restrict__ WdbB,
  const float* __restrict__ uxB, const float* __restrict__ h0B, const float* __restrict__ c0B,
  u16* __restrict__ out2,
  const float* __restrict__ ts)
{
  __shared__ __align__(16) u16 hb[16][280];
  __shared__ __align__(16) u16 cbuf[16][280];
  const int lstm = blockIdx.x >> 3;
  const int bbase = (blockIdx.x & 7) * 16;
  const u16* Wall = lstm ? WallB : WallA;
  const u16* Wd   = lstm ? WdB   : WdA;
  const float* Wdb= lstm ? WdbB  : WdbA;
  const float* ux = lstm ? uxB   : uxA;
  const float* h0 = lstm ? h0B   : h0A;
  const float* c0 = lstm ? c0B   : c0A;

  const int tid = threadIdx.x;
  const int l = tid & 63, w = tid >> 6;
  const int quad = l >> 4, lb = l & 15;
  const int b = bbase + lb;

  int jc[4], jr[4];
  #pragma unroll
  for (int jt=0;jt<4;jt++){ jc[jt] = w*64 + jt*16; jr[jt] = jc[jt] + quad*4; }

  float h[4][4], c[4][4];
  f32x4 bcs[4];
  #pragma unroll
  for (int jt=0;jt<4;jt++){
    f32x4 hv = *(const f32x4*)&h0[(long long)b*256 + jr[jt]];
    f32x4 cv = *(const f32x4*)&c0[(long long)b*256 + jr[jt]];
    bcs[jt] = *(const f32x4*)&Wdb[jr[jt]];
    us4 hp, cp;
    #pragma unroll
    for (int r=0;r<4;r++){ h[jt][r]=hv[r]; c[jt][r]=cv[r]; hp[r]=f2b(hv[r]); cp[r]=f2b(cv[r]); }
    *(us4*)&hb[lb][jr[jt]] = hp;
    *(us4*)&cbuf[lb][jr[jt]] = cp;
  }
  __syncthreads();

  for (int s=0;s<200;s++){
    float tsb = ts[(long long)b*200 + s];
    // c_s1 = tanh(c @ Wd^T + Wd_b)
    f32x4 ad[4];
    #pragma unroll
    for (int jt=0;jt<4;jt++) ad[jt] = bcs[jt];
    #pragma unroll
    for (int kk=0;kk<8;kk++){
      bf16x8 cf = *(const bf16x8*)&cbuf[lb][kk*32 + quad*8];
      #pragma unroll
      for (int jt=0;jt<4;jt++){
        bf16x8 wf = *(const bf16x8*)&Wd[(long long)(jc[jt]+lb)*256 + kk*32 + quad*8];
        ad[jt] = MFMA(wf, cf, ad[jt]);
      }
    }
    float cadj[4][4];
    #pragma unroll
    for (int jt=0;jt<4;jt++)
      #pragma unroll
      for (int r=0;r<4;r++){
        float cs1 = tanhx(ad[jt][r]);
        cadj[jt][r] = c[jt][r] + cs1*(tsb - 1.0f);
      }
    // gates = sigmoid(h @ Wall^T + ux)   (biases pre-folded into ux)
    f32x4 ag[4][4];
    long long uxrow = ((long long)b*200 + s)*1024;
    #pragma unroll
    for (int jt=0;jt<4;jt++)
      #pragma unroll
      for (int g=0;g<4;g++)
        ag[jt][g] = *(const f32x4*)&ux[uxrow + g*256 + jr[jt]];
    #pragma unroll
    for (int kk=0;kk<8;kk++){
      bf16x8 hf = *(const bf16x8*)&hb[lb][kk*32 + quad*8];
      #pragma unroll
      for (int jt=0;jt<4;jt++)
        #pragma unroll
        for (int g=0;g<4;g++){
          bf16x8 wf = *(const bf16x8*)&Wall[(long long)(g*256 + jc[jt] + lb)*256 + kk*32 + quad*8];
          ag[jt][g] = MFMA(wf, hf, ag[jt][g]);
        }
    }
    __syncthreads();   // all LDS reads for step s complete before overwrite
    long long orow = ((long long)b*200 + s)*256;
    #pragma unroll
    for (int jt=0;jt<4;jt++){
      f32x4 hv;
      us4 hp, cp;
      #pragma unroll
      for (int r=0;r<4;r++){
        float fg = sigm(ag[jt][0][r]);
        float ig = sigm(ag[jt][1][r]);
        float og = sigm(ag[jt][2][r]);
        float cg = sigm(ag[jt][3][r]);
        float cn = fg*cadj[jt][r] + ig*cg;
        float hn = og*tanhx(cn);
        c[jt][r]=cn; h[jt][r]=hn;
        hv[r]=hn; hp[r]=f2b(hn); cp[r]=f2b(cn);
      }
      if (lstm==0) *(f32x4*)&out1[orow + jr[jt]] = hv;
      else         *(us4*)&out2[orow + jr[jt]] = hp;
      *(us4*)&hb[lb][jr[jt]] = hp;
      *(us4*)&cbuf[lb][jr[jt]] = cp;
    }
    __syncthreads();
  }
}

// ---------------- attention E + softmax -> alpha ----------------
__global__ __launch_bounds__(256) void k_attn(const float* __restrict__ out1, const float* __restrict__ wa,
                                              float* __restrict__ alpha){
  __shared__ float was[256];
  __shared__ float buf[256];
  int b = blockIdx.x, tid = threadIdx.x;
  was[tid] = wa[tid];
  __syncthreads();
  float E = -1e30f;
  if (tid < 200){
    const float* row = out1 + ((long long)b*200 + tid)*256;
    float a0=0,a1=0,a2=0,a3=0;
    for (int j=0;j<256;j+=4){
      f32x4 v = *(const f32x4*)&row[j];
      a0 += v[0]*was[j]; a1 += v[1]*was[j+1]; a2 += v[2]*was[j+2]; a3 += v[3]*was[j+3];
    }
    E = (a0+a1)+(a2+a3);
  }
  buf[tid]=E; __syncthreads();
  for (int st=128; st>0; st>>=1){ if (tid<st) buf[tid]=fmaxf(buf[tid],buf[tid+st]); __syncthreads(); }
  float mx = buf[0]; __syncthreads();
  float e = (tid<200)? __expf(E-mx) : 0.f;
  buf[tid]=e; __syncthreads();
  for (int st=128; st>0; st>>=1){ if (tid<st) buf[tid]+=buf[tid+st]; __syncthreads(); }
  float sm = buf[0];
  if (tid<200) alpha[(long long)b*200+tid] = e/sm;
}

// ---------------- ctx reduction over seq ----------------
__global__ __launch_bounds__(256) void k_ctx(const float* __restrict__ P, float* __restrict__ ctx){
  int b = blockIdx.x, j = threadIdx.x;
  const float* p = P + (long long)b*200*256 + j;
  float a = 0.f;
  for (int s=0;s<200;s++) a += p[(long long)s*256];
  ctx[b*256+j] = a;
}

// ---------------- out = ctx @ Wout^T ----------------
__global__ __launch_bounds__(128) void k_out(const float* __restrict__ ctx, const float* __restrict__ Wout,
                                             float* __restrict__ out){
  __shared__ float cs[256];
  int b = blockIdx.x, t = threadIdx.x;
  cs[t] = ctx[b*256+t]; cs[t+128] = ctx[b*256+t+128];
  __syncthreads();
  const float* wr = Wout + (long long)t*256;
  float a0=0,a1=0,a2=0,a3=0;
  for (int j=0;j<256;j+=4){
    f32x4 v = *(const f32x4*)&wr[j];
    a0+=v[0]*cs[j]; a1+=v[1]*cs[j+1]; a2+=v[2]*cs[j+2]; a3+=v[3]*cs[j+3];
  }
  out[(long long)b*128 + t] = (a0+a1)+(a2+a3);
}

extern "C" void kernel_launch(void* const* d_in, const int* in_sizes, int n_in,
                              void* d_out, int out_size, void* d_ws, size_t ws_size,
                              hipStream_t stream)
{
  (void)in_sizes; (void)n_in; (void)out_size; (void)ws_size;
  const float* inputs = (const float*)d_in[0];
  const float* tstamp = (const float*)d_in[1];
  const float* emb    = (const float*)d_in[2];
  const float* Wall1w = (const float*)d_in[3];
  const float* Wall1b = (const float*)d_in[4];
  const float* Uall1w = (const float*)d_in[5];
  const float* Uall1b = (const float*)d_in[6];
  const float* Wd1w   = (const float*)d_in[7];
  const float* Wd1b   = (const float*)d_in[8];
  const float* Wall2w = (const float*)d_in[9];
  const float* Wall2b = (const float*)d_in[10];
  const float* Uall2w = (const float*)d_in[11];
  const float* Uall2b = (const float*)d_in[12];
  const float* Wd2w   = (const float*)d_in[13];
  const float* Wd2b   = (const float*)d_in[14];
  const float* wa     = (const float*)d_in[15];
  const float* Wbw    = (const float*)d_in[16];
  const float* Woutw  = (const float*)d_in[17];
  const float* h01    = (const float*)d_in[18];
  const float* c01    = (const float*)d_in[19];
  const float* h02    = (const float*)d_in[20];
  const float* c02    = (const float*)d_in[21];

  char* ws = (char*)d_ws;
  // ws layout (bytes); A0 region is reused for out1/out2/P/alpha/ctx after embed GEMM
  float* ux1   = (float*)(ws + 0);              // 25600*1024*4 = 104857600
  float* ux2   = (float*)(ws + 104857600LL);
  float* embF  = (float*)(ws + 209715200LL);    // 26214400
  u16*   embB  = (u16*)  (ws + 235929600LL);    // 13107200
  char*  scr   =          ws + 249036800LL;     // 72089600 scratch
  u16*   A0    = (u16*)scr;                     // 25600*1408*2 = 72089600
  float* out1  = (float*)scr;                   // 26214400 (after A0 dead)
  u16*   out2  = (u16*)  (scr + 26214400LL);    // 13107200
  float* P     = (float*)(scr + 39321600LL);    // 26214400
  float* alpha = (float*)(scr + 65536000LL);    // 102400
  float* ctx   = (float*)(scr + 65638400LL);    // 131072
  u16* embT    = (u16*)(ws + 321126400LL);      // 256*1408*2 = 720896
  u16* Wall1B  = (u16*)(ws + 321847296LL);      // 524288
  u16* Wall2B  = (u16*)(ws + 322371584LL);
  u16* Uall1B  = (u16*)(ws + 322895872LL);
  u16* Uall2B  = (u16*)(ws + 323420160LL);
  u16* Wd1B    = (u16*)(ws + 323944448LL);      // 131072
  u16* Wd2B    = (u16*)(ws + 324075520LL);
  u16* WbB     = (u16*)(ws + 324206592LL);
  // total ws needed: ~324.3 MB

  // 1) conversions
  k_cvt4<<<35200, 256, 0, stream>>>(inputs, A0, 1400, 1408, 25600LL*1408/4);
  k_tcvt<<<1408, 256, 0, stream>>>(emb, embT, 1400, 256, 1408);
  k_cvt4<<<256, 256, 0, stream>>>(Wall1w, Wall1B, 256, 256, 1024LL*256/4);
  k_cvt4<<<256, 256, 0, stream>>>(Wall2w, Wall2B, 256, 256, 1024LL*256/4);
  k_cvt4<<<256, 256, 0, stream>>>(Uall1w, Uall1B, 256, 256, 1024LL*256/4);
  k_cvt4<<<256, 256, 0, stream>>>(Uall2w, Uall2B, 256, 256, 1024LL*256/4);
  k_cvt4<<<64, 256, 0, stream>>>(Wd1w, Wd1B, 256, 256, 256LL*256/4);
  k_cvt4<<<64, 256, 0, stream>>>(Wd2w, Wd2B, 256, 256, 256LL*256/4);
  k_cvt4<<<64, 256, 0, stream>>>(Wbw, WbB, 256, 256, 256LL*256/4);

  // 2) embedded = inputs @ emb  (fp32 + bf16 copies)
  k_gemm<1><<<dim3(200,2), 256, 0, stream>>>(A0, embT, 256, 1408, embF, embB,
                                             nullptr, nullptr, nullptr, nullptr);
  // 3) ux = embedded @ Uall^T + (Uall_b + Wall_b)
  k_gemm<2><<<dim3(200,8), 256, 0, stream>>>(embB, Uall1B, 1024, 256, ux1, nullptr,
                                             Uall1b, Wall1b, nullptr, nullptr);
  k_gemm<2><<<dim3(200,8), 256, 0, stream>>>(embB, Uall2B, 1024, 256, ux2, nullptr,
                                             Uall2b, Wall2b, nullptr, nullptr);
  // 4) both TimeLSTM scans (persistent, 16 WGs)
  k_scan<<<16, 256, 0, stream>>>(Wall1B, Wd1B, Wd1b, ux1, h01, c01, out1,
                                 Wall2B, Wd2B, Wd2b, ux2, h02, c02, out2,
                                 tstamp);
  // 5) attention softmax
  k_attn<<<128, 256, 0, stream>>>(out1, wa, alpha);
  // 6) P = embedded * tanh(out2 @ Wb^T) * alpha
  k_gemm<3><<<dim3(200,2), 256, 0, stream>>>(out2, WbB, 256, 256, P, nullptr,
                                             nullptr, nullptr, embF, alpha);
  // 7) ctx = sum_s P ; out = ctx @ Wout^T
  k_ctx<<<128, 256, 0, stream>>>(P, ctx);
  k_out<<<128, 128, 0, stream>>>(ctx, Woutw, (float*)d_out);
}

// Round 2
// 1772.255 us; speedup vs baseline: 2.0423x; 2.0423x over previous
//
#include <hip/hip_runtime.h>

typedef unsigned short u16;
typedef unsigned long long u64;
typedef __attribute__((ext_vector_type(8))) short bf16x8;
typedef __attribute__((ext_vector_type(4))) float f32x4;
typedef __attribute__((ext_vector_type(4))) unsigned short us4;

#define MFMA(a,b,c) __builtin_amdgcn_mfma_f32_16x16x32_bf16((a),(b),(c),0,0,0)

// B=128, SEQ=200, VOCAB=1400 (pad 1408), D=H=256, 4H=1024, NCLS=128, M=B*SEQ=25600

static __device__ __forceinline__ u16 f2b(float f){
  unsigned u = __float_as_uint(f);
  u += 0x7fffu + ((u >> 16) & 1u);          // RNE fp32 -> bf16
  return (u16)(u >> 16);
}
static __device__ __forceinline__ float sigm(float x){ return 1.0f/(1.0f+__expf(-x)); }
static __device__ __forceinline__ float tanhx(float x){
  x = fminf(fmaxf(x, -15.f), 15.f);
  float e = __expf(-2.f*x);
  return (1.f - e)/(1.f + e);
}
static __device__ __forceinline__ void gl16(const void* g, void* l){
  __builtin_amdgcn_global_load_lds((const __attribute__((address_space(1))) void*)g,
                                   (__attribute__((address_space(3))) void*)l, 16, 0, 0);
}

// ---------------- fp32 -> bf16 convert (+ zero column pad) ----------------
__global__ __launch_bounds__(256) void k_cvt4(const float* __restrict__ src, u16* __restrict__ dst,
                                              int cin, int cout, long long tot4){
  long long i4 = (long long)blockIdx.x*256 + threadIdx.x;
  if (i4 >= tot4) return;
  long long o = i4*4;
  int r = (int)(o / cout);
  int c = (int)(o % cout);
  us4 d;
  if (c + 4 <= cin){
    f32x4 v = *(const f32x4*)&src[(long long)r*cin + c];
    d[0]=f2b(v[0]); d[1]=f2b(v[1]); d[2]=f2b(v[2]); d[3]=f2b(v[3]);
  } else {
    for (int k=0;k<4;k++){ int cc=c+k; d[k] = (cc<cin)? f2b(src[(long long)r*cin+cc]) : (u16)0; }
  }
  *(us4*)&dst[(long long)r*cout + c] = d;
}

// emb [K=1400][N=256] -> dst [N=256][Kp=1408] bf16 (transposed, padded)
__global__ __launch_bounds__(256) void k_tcvt(const float* __restrict__ src, u16* __restrict__ dst,
                                              int K, int N, int Kp){
  int idx = blockIdx.x*256 + threadIdx.x;
  if (idx >= N*Kp) return;
  int n = idx / Kp, k = idx % Kp;
  dst[idx] = (k < K) ? f2b(src[(long long)k*N + n]) : (u16)0;
}

// ---------------- fused weight conversions (7 contiguous arrays) ----------
__global__ __launch_bounds__(256) void k_cvtw(
  const float* __restrict__ s0, const float* __restrict__ s1, const float* __restrict__ s2,
  const float* __restrict__ s3, const float* __restrict__ s4, const float* __restrict__ s5,
  const float* __restrict__ s6,
  u16* __restrict__ d0, u16* __restrict__ d1, u16* __restrict__ d2, u16* __restrict__ d3,
  u16* __restrict__ d4, u16* __restrict__ d5, u16* __restrict__ d6)
{
  long long q = (long long)blockIdx.x*256 + threadIdx.x;   // quad index
  const float* src; u16* dst; long long rel;
  if      (q < 65536)  { src=s0; dst=d0; rel=q; }
  else if (q < 131072) { src=s1; dst=d1; rel=q-65536; }
  else if (q < 196608) { src=s2; dst=d2; rel=q-131072; }
  else if (q < 262144) { src=s3; dst=d3; rel=q-196608; }
  else if (q < 278528) { src=s4; dst=d4; rel=q-262144; }
  else if (q < 294912) { src=s5; dst=d5; rel=q-278528; }
  else if (q < 311296) { src=s6; dst=d6; rel=q-294912; }
  else return;
  long long o = rel*4;
  f32x4 v = *(const f32x4*)&src[o];
  us4 d; d[0]=f2b(v[0]); d[1]=f2b(v[1]); d[2]=f2b(v[2]); d[3]=f2b(v[3]);
  *(us4*)&dst[o] = d;
}

// ---------------- init: zero E + flags (ws re-poisoned each launch) -------
__global__ __launch_bounds__(256) void k_init(float* __restrict__ E, int* __restrict__ flags){
  int i = blockIdx.x*256 + threadIdx.x;
  if (i < 25600) E[i] = 0.f;
  if (i < 16) flags[i] = 0;
}

// ---------------- bf16 MFMA GEMM: C[M,N] = A[M,K] * Bt[N,K]^T -------------
// EPI: 1 = write fp32 + bf16 copies; 2 = +bias1[col]+bias2[col], fp32;
//      3 = P = emb[row,col] * tanh(acc) * alpha[row], fp32
template<int EPI>
__global__ __launch_bounds__(256) void k_gemm(const u16* __restrict__ A, const u16* __restrict__ Bt,
    int N, int K,
    float* __restrict__ Cf, u16* __restrict__ Cb,
    const float* __restrict__ bias1, const float* __restrict__ bias2,
    const float* __restrict__ emb, const float* __restrict__ alpha)
{
  __shared__ __align__(16) u16 As[128*64];
  __shared__ __align__(16) u16 Bs[128*64];
  const int tid = threadIdx.x;
  const int l = tid & 63, w = tid >> 6;
  const int quad = l >> 4, lb = l & 15;
  const int wr = w >> 1, wc = w & 1;
  const long long m0 = (long long)blockIdx.x * 128;
  const int n0 = blockIdx.y * 128;

  f32x4 acc[4][4];
  #pragma unroll
  for (int i=0;i<4;i++)
    #pragma unroll
    for (int j=0;j<4;j++) acc[i][j] = (f32x4){0.f,0.f,0.f,0.f};

  for (int kk = 0; kk < K; kk += 64){
    #pragma unroll
    for (int it=0; it<4; ++it){      // 128x64 bf16 tile, XOR-swizzled 16B slots
      int slot = it*256 + tid;
      int m = slot >> 3;
      int q = (slot & 7) ^ (m & 7);
      gl16(A + (m0+m)*K + kk + q*8, &As[slot*8]);
    }
    #pragma unroll
    for (int it=0; it<4; ++it){
      int slot = it*256 + tid;
      int m = slot >> 3;
      int q = (slot & 7) ^ (m & 7);
      gl16(Bt + (long long)(n0+m)*K + kk + q*8, &Bs[slot*8]);
    }
    __syncthreads();
    #pragma unroll
    for (int ks=0; ks<2; ++ks){
      int kq = quad + ks*4;
      bf16x8 af[4], bfr[4];
      #pragma unroll
      for (int i=0;i<4;i++){ int m = wr*64 + i*16 + lb; af[i]  = *(const bf16x8*)&As[m*64 + ((kq ^ (m&7))*8)]; }
      #pragma unroll
      for (int j=0;j<4;j++){ int n = wc*64 + j*16 + lb; bfr[j] = *(const bf16x8*)&Bs[n*64 + ((kq ^ (n&7))*8)]; }
      #pragma unroll
      for (int i=0;i<4;i++)
        #pragma unroll
        for (int j=0;j<4;j++)
          acc[i][j] = MFMA(af[i], bfr[j], acc[i][j]);
    }
    __syncthreads();
  }
  #pragma unroll
  for (int i=0;i<4;i++){
    #pragma unroll
    for (int j=0;j<4;j++){
      int col = n0 + wc*64 + j*16 + lb;
      #pragma unroll
      for (int r=0;r<4;r++){
        long long row = m0 + wr*64 + i*16 + quad*4 + r;
        long long o = row*N + col;
        float v = acc[i][j][r];
        if (EPI==1){ Cf[o]=v; Cb[o]=f2b(v); }
        else if (EPI==2){ Cf[o] = v + bias1[col] + bias2[col]; }
        else if (EPI==3){ Cf[o] = emb[o] * tanhx(v) * alpha[row]; }
        else { Cf[o]=v; }
      }
    }
  }
}

// ---------------- persistent TimeLSTM scan, weights in registers ----------
// 64 WGs: bi>>5 = lstm, (bi>>2)&7 = batch chunk of 16, bi&3 = j-chunk of 64.
// Groups of 4 (same lstm+bchunk) exchange h,c each step via IF-coherent
// agent-scope atomics + per-group flag. Wall/Wd fragments live in VGPRs.
__global__ __launch_bounds__(256,1) void k_scan(
  const u16* __restrict__ Wall1, const u16* __restrict__ Wd1, const float* __restrict__ Wd1b,
  const float* __restrict__ ux1, const float* __restrict__ h01, const float* __restrict__ c01,
  const u16* __restrict__ Wall2, const u16* __restrict__ Wd2, const float* __restrict__ Wd2b,
  const float* __restrict__ ux2, const float* __restrict__ h02, const float* __restrict__ c02,
  const float* __restrict__ ts, const float* __restrict__ wa,
  float* __restrict__ E, u16* __restrict__ out2,
  u16* __restrict__ hx, u16* __restrict__ cx, int* __restrict__ flags)
{
  __shared__ __align__(16) u16 hb[16][264];
  __shared__ __align__(16) u16 cb[16][264];
  const int bi = blockIdx.x;
  const int lstm = bi >> 5;
  const int bc   = (bi >> 2) & 7;
  const int jw   = bi & 3;
  const int grp  = bi >> 2;            // 0..15, distinct per (lstm,bc)
  const u16* Wall  = lstm ? Wall2 : Wall1;
  const u16* Wd    = lstm ? Wd2   : Wd1;
  const float* Wdb = lstm ? Wd2b  : Wd1b;
  const float* ux  = lstm ? ux2   : ux1;
  const float* h0  = lstm ? h02   : h01;
  const float* c0  = lstm ? c02   : c01;

  const int tid = threadIdx.x;
  const int l = tid & 63, w = tid >> 6;
  const int quad = l >> 4, lb = l & 15;
  const int bg = bc*16 + lb;            // lane's global batch
  const int jwave = jw*64 + w*16;       // wave's 16 output rows (per gate)
  const int jlane = jwave + quad*4;     // lane's 4 j rows (C-layout)

  // ---- one-time: weight fragments into registers (A-frag: m=lb, k=quad*8+i)
  bf16x8 wfA[4][8], wdA[8];
  #pragma unroll
  for (int g=0; g<4; ++g)
    #pragma unroll
    for (int kk=0; kk<8; ++kk)
      wfA[g][kk] = *(const bf16x8*)&Wall[(long long)(g*256 + jwave + lb)*256 + kk*32 + quad*8];
  #pragma unroll
  for (int kk=0; kk<8; ++kk)
    wdA[kk] = *(const bf16x8*)&Wd[(long long)(jwave + lb)*256 + kk*32 + quad*8];

  f32x4 bcs  = *(const f32x4*)&Wdb[jlane];
  f32x4 wav  = *(const f32x4*)&wa[jlane];
  f32x4 creg = *(const f32x4*)&c0[(long long)bg*256 + jlane];

  // ---- init LDS h/c (full 256 j for our 16 batches), bf16
  {
    int bb = tid >> 4, j0 = (tid & 15) * 16;
    #pragma unroll
    for (int kq=0; kq<4; ++kq){
      f32x4 hv = *(const f32x4*)&h0[(long long)(bc*16+bb)*256 + j0 + kq*4];
      f32x4 cv = *(const f32x4*)&c0[(long long)(bc*16+bb)*256 + j0 + kq*4];
      us4 hp, cp;
      #pragma unroll
      for (int r=0;r<4;++r){ hp[r]=f2b(hv[r]); cp[r]=f2b(cv[r]); }
      *(us4*)&hb[bb][j0+kq*4] = hp;
      *(us4*)&cb[bb][j0+kq*4] = cp;
    }
  }
  __syncthreads();

  f32x4 uxr[4];
  #pragma unroll
  for (int g=0; g<4; ++g)
    uxr[g] = *(const f32x4*)&ux[(long long)bg*200*1024 + g*256 + jlane];
  float tcur = ts[(long long)bg*200];

  for (int s=0; s<200; ++s){
    // c_s1 pre-act: Wd GEMV over cb
    f32x4 ad = bcs;
    #pragma unroll
    for (int kk=0;kk<8;++kk){
      bf16x8 cf = *(const bf16x8*)&cb[lb][kk*32 + quad*8];
      ad = MFMA(wdA[kk], cf, ad);
    }
    // gates: ux + Wall GEMV over hb
    f32x4 ag[4];
    #pragma unroll
    for (int g=0; g<4; ++g) ag[g] = uxr[g];
    #pragma unroll
    for (int kk=0;kk<8;++kk){
      bf16x8 hf = *(const bf16x8*)&hb[lb][kk*32 + quad*8];
      #pragma unroll
      for (int g=0; g<4; ++g) ag[g] = MFMA(wfA[g][kk], hf, ag[g]);
    }
    // prefetch next step's ux/ts (independent)
    float tnext = 0.f;
    if (s < 199){
      #pragma unroll
      for (int g=0; g<4; ++g)
        uxr[g] = *(const f32x4*)&ux[((long long)bg*200 + s+1)*1024 + g*256 + jlane];
      tnext = ts[(long long)bg*200 + s+1];
    }
    // elementwise update (fp32 c carried in regs)
    f32x4 hn; us4 hp, cp;
    #pragma unroll
    for (int r=0;r<4;++r){
      float cs1 = tanhx(ad[r]);
      float cadj = creg[r] + cs1*(tcur - 1.0f);
      float fg = sigm(ag[0][r]);
      float ig = sigm(ag[1][r]);
      float og = sigm(ag[2][r]);
      float cg = sigm(ag[3][r]);
      float cn = fg*cadj + ig*cg;
      float hv = og*tanhx(cn);
      creg[r]=cn; hn[r]=hv;
      hp[r]=f2b(hv); cp[r]=f2b(cn);
    }
    tcur = tnext;
    // outputs: lstm0 -> E partial (folded attention dot), lstm1 -> out2
    if (lstm==0){
      float e = hn[0]*wav[0] + hn[1]*wav[1] + hn[2]*wav[2] + hn[3]*wav[3];
      e += __shfl_xor(e, 16, 64);
      e += __shfl_xor(e, 32, 64);
      if (l < 16) atomicAdd(&E[(long long)bg*200 + s], e);
    } else {
      *(us4*)&out2[((long long)bg*200 + s)*256 + jlane] = hp;
    }
    // exchange h,c with the 3 sibling j-WGs
    if (s < 199){
      int slot = (s+1)&1;
      u64 hv64, cv64;
      __builtin_memcpy(&hv64,&hp,8); __builtin_memcpy(&cv64,&cp,8);
      long long xbase = ((long long)(slot*16 + grp)*16 + lb)*256 + jlane;
      __hip_atomic_store((u64*)&hx[xbase], hv64, __ATOMIC_RELAXED, __HIP_MEMORY_SCOPE_AGENT);
      __hip_atomic_store((u64*)&cx[xbase], cv64, __ATOMIC_RELAXED, __HIP_MEMORY_SCOPE_AGENT);
      __syncthreads();                       // drains vmcnt for all waves
      if (tid == 0){
        __hip_atomic_fetch_add(&flags[grp], 1, __ATOMIC_RELEASE, __HIP_MEMORY_SCOPE_AGENT);
        int target = 4*(s+1);
        while (__hip_atomic_load(&flags[grp], __ATOMIC_ACQUIRE, __HIP_MEMORY_SCOPE_AGENT) < target)
          __builtin_amdgcn_s_sleep(1);
      }
      __syncthreads();
      // refill LDS h/c from exchange (IF-direct loads)
      int bb = tid >> 4, j0 = (tid & 15) * 16;
      long long rbase = ((long long)(slot*16 + grp)*16 + bb)*256 + j0;
      u64 hvv[4], cvv[4];
      #pragma unroll
      for (int kq=0;kq<4;++kq){
        hvv[kq] = __hip_atomic_load((const u64*)&hx[rbase + kq*4], __ATOMIC_RELAXED, __HIP_MEMORY_SCOPE_AGENT);
        cvv[kq] = __hip_atomic_load((const u64*)&cx[rbase + kq*4], __ATOMIC_RELAXED, __HIP_MEMORY_SCOPE_AGENT);
      }
      #pragma unroll
      for (int kq=0;kq<4;++kq){
        *(u64*)&hb[bb][j0+kq*4] = hvv[kq];
        *(u64*)&cb[bb][j0+kq*4] = cvv[kq];
      }
      __syncthreads();
    }
  }
}

// ---------------- softmax over precomputed E -> alpha ----------------
__global__ __launch_bounds__(256) void k_attn(const float* __restrict__ E, float* __restrict__ alpha){
  __shared__ float buf[256];
  int b = blockIdx.x, tid = threadIdx.x;
  float Ev = (tid < 200) ? E[(long long)b*200 + tid] : -1e30f;
  buf[tid]=Ev; __syncthreads();
  for (int st=128; st>0; st>>=1){ if (tid<st) buf[tid]=fmaxf(buf[tid],buf[tid+st]); __syncthreads(); }
  float mx = buf[0]; __syncthreads();
  float e = (tid<200)? __expf(Ev-mx) : 0.f;
  buf[tid]=e; __syncthreads();
  for (int st=128; st>0; st>>=1){ if (tid<st) buf[tid]+=buf[tid+st]; __syncthreads(); }
  float sm = buf[0];
  if (tid<200) alpha[(long long)b*200+tid] = e/sm;
}

// ---------------- ctx reduction over seq ----------------
__global__ __launch_bounds__(256) void k_ctx(const float* __restrict__ P, float* __restrict__ ctx){
  int b = blockIdx.x, j = threadIdx.x;
  const float* p = P + (long long)b*200*256 + j;
  float a = 0.f;
  for (int s=0;s<200;s++) a += p[(long long)s*256];
  ctx[b*256+j] = a;
}

// ---------------- out = ctx @ Wout^T ----------------
__global__ __launch_bounds__(128) void k_out(const float* __restrict__ ctx, const float* __restrict__ Wout,
                                             float* __restrict__ out){
  __shared__ float cs[256];
  int b = blockIdx.x, t = threadIdx.x;
  cs[t] = ctx[b*256+t]; cs[t+128] = ctx[b*256+t+128];
  __syncthreads();
  const float* wr = Wout + (long long)t*256;
  float a0=0,a1=0,a2=0,a3=0;
  for (int j=0;j<256;j+=4){
    f32x4 v = *(const f32x4*)&wr[j];
    a0+=v[0]*cs[j]; a1+=v[1]*cs[j+1]; a2+=v[2]*cs[j+2]; a3+=v[3]*cs[j+3];
  }
  out[(long long)b*128 + t] = (a0+a1)+(a2+a3);
}

extern "C" void kernel_launch(void* const* d_in, const int* in_sizes, int n_in,
                              void* d_out, int out_size, void* d_ws, size_t ws_size,
                              hipStream_t stream)
{
  (void)in_sizes; (void)n_in; (void)out_size; (void)ws_size;
  const float* inputs = (const float*)d_in[0];
  const float* tstamp = (const float*)d_in[1];
  const float* emb    = (const float*)d_in[2];
  const float* Wall1w = (const float*)d_in[3];
  const float* Wall1b = (const float*)d_in[4];
  const float* Uall1w = (const float*)d_in[5];
  const float* Uall1b = (const float*)d_in[6];
  const float* Wd1w   = (const float*)d_in[7];
  const float* Wd1b   = (const float*)d_in[8];
  const float* Wall2w = (const float*)d_in[9];
  const float* Wall2b = (const float*)d_in[10];
  const float* Uall2w = (const float*)d_in[11];
  const float* Uall2b = (const float*)d_in[12];
  const float* Wd2w   = (const float*)d_in[13];
  const float* Wd2b   = (const float*)d_in[14];
  const float* wa     = (const float*)d_in[15];
  const float* Wbw    = (const float*)d_in[16];
  const float* Woutw  = (const float*)d_in[17];
  const float* h01    = (const float*)d_in[18];
  const float* c01    = (const float*)d_in[19];
  const float* h02    = (const float*)d_in[20];
  const float* c02    = (const float*)d_in[21];

  char* ws = (char*)d_ws;
  float* ux1   = (float*)(ws + 0);              // 104857600
  float* ux2   = (float*)(ws + 104857600LL);
  float* embF  = (float*)(ws + 209715200LL);    // 26214400
  u16*   embB  = (u16*)  (ws + 235929600LL);    // 13107200
  char*  scr   =          ws + 249036800LL;     // 72089600 region
  u16*   A0    = (u16*)scr;                     // 72089600 (dead after embed GEMM)
  u16*   out2  = (u16*)  (scr + 0);             // 13107200
  float* P     = (float*)(scr + 13107200LL);    // 26214400
  float* alpha = (float*)(scr + 39321600LL);    // 102400
  float* ctx   = (float*)(scr + 39424000LL);    // 131072
  float* E     = (float*)(scr + 39555072LL);    // 102400
  u16*   hx    = (u16*)  (scr + 39657472LL);    // 262144
  u16*   cx    = (u16*)  (scr + 39919616LL);    // 262144
  int*   flags = (int*)  (scr + 40181760LL);    // 64
  u16* embT    = (u16*)(ws + 321126400LL);      // 720896
  u16* Wall1B  = (u16*)(ws + 321847296LL);      // 524288
  u16* Wall2B  = (u16*)(ws + 322371584LL);
  u16* Uall1B  = (u16*)(ws + 322895872LL);
  u16* Uall2B  = (u16*)(ws + 323420160LL);
  u16* Wd1B    = (u16*)(ws + 323944448LL);      // 131072
  u16* Wd2B    = (u16*)(ws + 324075520LL);
  u16* WbB     = (u16*)(ws + 324206592LL);
  // total ws: ~324.3 MB (same as passing round-1 layout)

  // 1) conversions
  k_cvt4<<<35200, 256, 0, stream>>>(inputs, A0, 1400, 1408, 25600LL*1408/4);
  k_tcvt<<<1408, 256, 0, stream>>>(emb, embT, 1400, 256, 1408);
  k_cvtw<<<1216, 256, 0, stream>>>(Wall1w, Wall2w, Uall1w, Uall2w, Wd1w, Wd2w, Wbw,
                                   Wall1B, Wall2B, Uall1B, Uall2B, Wd1B, Wd2B, WbB);
  // 2) embedded = inputs @ emb  (fp32 + bf16 copies)
  k_gemm<1><<<dim3(200,2), 256, 0, stream>>>(A0, embT, 256, 1408, embF, embB,
                                             nullptr, nullptr, nullptr, nullptr);
  // 3) ux = embedded @ Uall^T + (Uall_b + Wall_b)
  k_gemm<2><<<dim3(200,8), 256, 0, stream>>>(embB, Uall1B, 1024, 256, ux1, nullptr,
                                             Uall1b, Wall1b, nullptr, nullptr);
  k_gemm<2><<<dim3(200,8), 256, 0, stream>>>(embB, Uall2B, 1024, 256, ux2, nullptr,
                                             Uall2b, Wall2b, nullptr, nullptr);
  // 4) zero E + group flags (after A0 is dead: E/hx/cx/flags overlap A0)
  k_init<<<100, 256, 0, stream>>>(E, flags);
  // 5) both TimeLSTM scans (64 persistent WGs, register-resident weights)
  k_scan<<<64, 256, 0, stream>>>(Wall1B, Wd1B, Wd1b, ux1, h01, c01,
                                 Wall2B, Wd2B, Wd2b, ux2, h02, c02,
                                 tstamp, wa, E, out2, hx, cx, flags);
  // 6) alpha = softmax(E)
  k_attn<<<128, 256, 0, stream>>>(E, alpha);
  // 7) P = embedded * tanh(out2 @ Wb^T) * alpha
  k_gemm<3><<<dim3(200,2), 256, 0, stream>>>(out2, WbB, 256, 256, P, nullptr,
                                             nullptr, nullptr, embF, alpha);
  // 8) ctx = sum_s P ; out = ctx @ Wout^T
  k_ctx<<<128, 256, 0, stream>>>(P, ctx);
  k_out<<<128, 128, 0, stream>>>(ctx, Woutw, (float*)d_out);
}

// Round 3
// 1139.981 us; speedup vs baseline: 3.1750x; 1.5546x over previous
//
#include <hip/hip_runtime.h>

typedef unsigned short u16;
typedef unsigned long long u64;
typedef __attribute__((ext_vector_type(8))) short bf16x8;
typedef __attribute__((ext_vector_type(4))) float f32x4;
typedef __attribute__((ext_vector_type(4))) unsigned short us4;

#define MFMA(a,b,c) __builtin_amdgcn_mfma_f32_16x16x32_bf16((a),(b),(c),0,0,0)
#define KEEP(x) asm volatile("" : "+v"(x))

// B=128, SEQ=200, VOCAB=1400 (pad 1408), D=H=256, 4H=1024, NCLS=128, M=B*SEQ=25600

static __device__ __forceinline__ u16 f2b(float f){
  unsigned u = __float_as_uint(f);
  u += 0x7fffu + ((u >> 16) & 1u);          // RNE fp32 -> bf16
  return (u16)(u >> 16);
}
static __device__ __forceinline__ float sigm(float x){ return 1.0f/(1.0f+__expf(-x)); }
static __device__ __forceinline__ float tanhx(float x){
  x = fminf(fmaxf(x, -15.f), 15.f);
  float e = __expf(-2.f*x);
  return (1.f - e)/(1.f + e);
}
static __device__ __forceinline__ void gl16(const void* g, void* l){
  __builtin_amdgcn_global_load_lds((const __attribute__((address_space(1))) void*)g,
                                   (__attribute__((address_space(3))) void*)l, 16, 0, 0);
}

// ---------------- fused prep: inputs cvt + emb transpose-cvt + weights ----
__global__ __launch_bounds__(256) void k_prep(
  const float* __restrict__ in0, u16* __restrict__ A0,
  const float* __restrict__ emb, u16* __restrict__ embT,
  const float* __restrict__ s0, const float* __restrict__ s1, const float* __restrict__ s2,
  const float* __restrict__ s3, const float* __restrict__ s4, const float* __restrict__ s5,
  const float* __restrict__ s6,
  u16* __restrict__ d0, u16* __restrict__ d1, u16* __restrict__ d2, u16* __restrict__ d3,
  u16* __restrict__ d4, u16* __restrict__ d5, u16* __restrict__ d6)
{
  int bx = blockIdx.x, tid = threadIdx.x;
  if (bx < 35200){                     // inputs [25600 x 1400] -> bf16 padded 1408
    long long i4 = (long long)bx*256 + tid;      // < 9011200 exactly
    long long o = i4*4;
    int r = (int)(o / 1408);
    int c = (int)(o % 1408);
    us4 d;
    if (c + 4 <= 1400){
      f32x4 v = *(const f32x4*)&in0[(long long)r*1400 + c];
      d[0]=f2b(v[0]); d[1]=f2b(v[1]); d[2]=f2b(v[2]); d[3]=f2b(v[3]);
    } else {
      for (int k=0;k<4;k++){ int cc=c+k; d[k] = (cc<1400)? f2b(in0[(long long)r*1400+cc]) : (u16)0; }
    }
    *(us4*)&A0[(long long)r*1408 + c] = d;
  } else if (bx < 36608){              // emb [1400x256] -> embT [256x1408] bf16
    int idx = (bx-35200)*256 + tid;    // < 360448 exactly
    int n = idx / 1408, k = idx % 1408;
    embT[idx] = (k < 1400) ? f2b(emb[(long long)k*256 + n]) : (u16)0;
  } else {                             // 7 weight arrays fp32 -> bf16
    long long q = (long long)(bx-36608)*256 + tid;   // < 311296 exactly
    const float* src; u16* dst; long long rel;
    if      (q < 65536)  { src=s0; dst=d0; rel=q; }
    else if (q < 131072) { src=s1; dst=d1; rel=q-65536; }
    else if (q < 196608) { src=s2; dst=d2; rel=q-131072; }
    else if (q < 262144) { src=s3; dst=d3; rel=q-196608; }
    else if (q < 278528) { src=s4; dst=d4; rel=q-262144; }
    else if (q < 294912) { src=s5; dst=d5; rel=q-278528; }
    else                 { src=s6; dst=d6; rel=q-294912; }
    long long o = rel*4;
    f32x4 v = *(const f32x4*)&src[o];
    us4 d; d[0]=f2b(v[0]); d[1]=f2b(v[1]); d[2]=f2b(v[2]); d[3]=f2b(v[3]);
    *(us4*)&dst[o] = d;
  }
}

// ---------------- init: zero E + ctx (ws re-poisoned each launch) ---------
__global__ __launch_bounds__(256) void k_init(float* __restrict__ E, float* __restrict__ ctx){
  int i = blockIdx.x*256 + threadIdx.x;     // 228*256 = 58368 exactly
  if (i < 25600) E[i] = 0.f;
  else ctx[i-25600] = 0.f;                  // 32768
}

// ---------------- bf16 MFMA GEMM: C[M,N] = A[M,K] * Bt[N,K]^T -------------
// EPI 1: write fp32 + bf16 copies
// EPI 4: dual-output ux GEMM, +bias pair, fp32 (blockIdx.y>=8 -> second set)
// EPI 5: ctx[b,col] += emb[row,col]*tanh(acc)*alpha[row]  (LDS + global atomics)
template<int EPI>
__global__ __launch_bounds__(256) void k_gemm(const u16* __restrict__ A, const u16* __restrict__ Bt,
    int N, int K,
    float* __restrict__ Cf, u16* __restrict__ Cb,
    const float* __restrict__ bias1, const float* __restrict__ bias2,
    const u16* __restrict__ Bt2, float* __restrict__ Cf2,
    const float* __restrict__ bias3, const float* __restrict__ bias4,
    const float* __restrict__ emb, const float* __restrict__ alpha)
{
  __shared__ __align__(16) u16 As[128*64];
  __shared__ __align__(16) u16 Bs[128*64];
  __shared__ float red[2][128];
  const int tid = threadIdx.x;
  const int l = tid & 63, w = tid >> 6;
  const int quad = l >> 4, lb = l & 15;
  const int wr = w >> 1, wc = w & 1;
  const long long m0 = (long long)blockIdx.x * 128;
  int n0 = blockIdx.y * 128;
  if (EPI==4 && blockIdx.y >= 8){
    Bt = Bt2; Cf = Cf2; bias1 = bias3; bias2 = bias4; n0 = (blockIdx.y-8)*128;
  }

  f32x4 acc[4][4];
  #pragma unroll
  for (int i=0;i<4;i++)
    #pragma unroll
    for (int j=0;j<4;j++) acc[i][j] = (f32x4){0.f,0.f,0.f,0.f};

  for (int kk = 0; kk < K; kk += 64){
    #pragma unroll
    for (int it=0; it<4; ++it){      // 128x64 bf16 tile, XOR-swizzled 16B slots
      int slot = it*256 + tid;
      int m = slot >> 3;
      int q = (slot & 7) ^ (m & 7);
      gl16(A + (m0+m)*K + kk + q*8, &As[slot*8]);
    }
    #pragma unroll
    for (int it=0; it<4; ++it){
      int slot = it*256 + tid;
      int m = slot >> 3;
      int q = (slot & 7) ^ (m & 7);
      gl16(Bt + (long long)(n0+m)*K + kk + q*8, &Bs[slot*8]);
    }
    __syncthreads();
    #pragma unroll
    for (int ks=0; ks<2; ++ks){
      int kq = quad + ks*4;
      bf16x8 af[4], bfr[4];
      #pragma unroll
      for (int i=0;i<4;i++){ int m = wr*64 + i*16 + lb; af[i]  = *(const bf16x8*)&As[m*64 + ((kq ^ (m&7))*8)]; }
      #pragma unroll
      for (int j=0;j<4;j++){ int n = wc*64 + j*16 + lb; bfr[j] = *(const bf16x8*)&Bs[n*64 + ((kq ^ (n&7))*8)]; }
      #pragma unroll
      for (int i=0;i<4;i++)
        #pragma unroll
        for (int j=0;j<4;j++)
          acc[i][j] = MFMA(af[i], bfr[j], acc[i][j]);
    }
    __syncthreads();
  }

  if (EPI==5){
    const int b0 = (int)(m0 / 200);
    red[tid>>7][tid&127] = 0.f;
    __syncthreads();
    #pragma unroll
    for (int i=0;i<4;i++){
      #pragma unroll
      for (int j=0;j<4;j++){
        int col = wc*64 + j*16 + lb;          // 0..127 within n0 tile
        #pragma unroll
        for (int r=0;r<4;r++){
          long long row = m0 + wr*64 + i*16 + quad*4 + r;
          long long o = row*N + n0 + col;
          float v = emb[o] * tanhx(acc[i][j][r]) * alpha[row];
          atomicAdd(&red[(int)(row/200) - b0][col], v);
        }
      }
    }
    __syncthreads();
    int bl = tid >> 7, col = tid & 127;       // 256 threads cover [2][128]
    int bb = b0 + bl;
    if (bb < 128) atomicAdd(&Cf[bb*256 + n0 + col], red[bl][col]);
    return;
  }

  #pragma unroll
  for (int i=0;i<4;i++){
    #pragma unroll
    for (int j=0;j<4;j++){
      int col = n0 + wc*64 + j*16 + lb;
      #pragma unroll
      for (int r=0;r<4;r++){
        long long row = m0 + wr*64 + i*16 + quad*4 + r;
        long long o = row*N + col;
        float v = acc[i][j][r];
        if (EPI==1){ Cf[o]=v; Cb[o]=f2b(v); }
        else { Cf[o] = v + bias1[col] + bias2[col]; }   // EPI 4
      }
    }
  }
}

// ---------------- persistent TimeLSTM scan, weights in registers ----------
// 64 WGs: bi>>5 = lstm, (bi>>2)&7 = batch chunk of 16, bi&3 = j-chunk of 64.
// Sibling exchange: relaxed agent-scope data stores -> barrier (vmcnt drain =
// MALL ack) -> tid0 publishes seq word (exact step value; poison never
// matches) -> per-thread poll of its writer's seq -> relaxed refill loads.
// No release/acquire fences => no buffer_wbl2 / buffer_inv per step.
__global__ __launch_bounds__(256,1) void k_scan(
  const u16* __restrict__ Wall1, const u16* __restrict__ Wd1, const float* __restrict__ Wd1b,
  const float* __restrict__ ux1, const float* __restrict__ h01, const float* __restrict__ c01,
  const u16* __restrict__ Wall2, const u16* __restrict__ Wd2, const float* __restrict__ Wd2b,
  const float* __restrict__ ux2, const float* __restrict__ h02, const float* __restrict__ c02,
  const float* __restrict__ ts, const float* __restrict__ wa,
  float* __restrict__ E, u16* __restrict__ out2,
  u16* __restrict__ hx, u16* __restrict__ cx, int* __restrict__ seqw)
{
  __shared__ __align__(16) u16 hb[16][264];
  __shared__ __align__(16) u16 cb[16][264];
  const int bi = blockIdx.x;
  const int lstm = bi >> 5;
  const int bc   = (bi >> 2) & 7;
  const int jw   = bi & 3;
  const int grp  = bi >> 2;            // 0..15, distinct per (lstm,bc)
  const u16* Wall  = lstm ? Wall2 : Wall1;
  const u16* Wd    = lstm ? Wd2   : Wd1;
  const float* Wdb = lstm ? Wd2b  : Wd1b;
  const float* ux  = lstm ? ux2   : ux1;
  const float* h0  = lstm ? h02   : h01;
  const float* c0  = lstm ? c02   : c01;

  const int tid = threadIdx.x;
  const int l = tid & 63, w = tid >> 6;
  const int quad = l >> 4, lb = l & 15;
  const int bg = bc*16 + lb;            // lane's global batch
  const int jwave = jw*64 + w*16;       // wave's 16 output rows (per gate)
  const int jlane = jwave + quad*4;     // lane's 4 j rows (C-layout)
  // refill role
  const int bb = tid >> 4, jj = tid & 15, j0 = jj*16;
  const int wjw = jj >> 2;              // writer WG of my refill block

  // ---- one-time: weight fragments into registers (A-frag: m=lb, k=quad*8+i)
  bf16x8 wfA[4][8], wdA[8];
  #pragma unroll
  for (int g=0; g<4; ++g)
    #pragma unroll
    for (int kk=0; kk<8; ++kk){
      wfA[g][kk] = *(const bf16x8*)&Wall[(long long)(g*256 + jwave + lb)*256 + kk*32 + quad*8];
      KEEP(wfA[g][kk]);
    }
  #pragma unroll
  for (int kk=0; kk<8; ++kk){
    wdA[kk] = *(const bf16x8*)&Wd[(long long)(jwave + lb)*256 + kk*32 + quad*8];
    KEEP(wdA[kk]);
  }

  f32x4 bcs  = *(const f32x4*)&Wdb[jlane];
  f32x4 wav  = *(const f32x4*)&wa[jlane];
  f32x4 creg = *(const f32x4*)&c0[(long long)bg*256 + jlane];

  // ---- init LDS h/c (full 256 j for our 16 batches), bf16
  {
    #pragma unroll
    for (int kq=0; kq<4; ++kq){
      f32x4 hv = *(const f32x4*)&h0[(long long)(bc*16+bb)*256 + j0 + kq*4];
      f32x4 cv = *(const f32x4*)&c0[(long long)(bc*16+bb)*256 + j0 + kq*4];
      us4 hp, cp;
      #pragma unroll
      for (int r=0;r<4;++r){ hp[r]=f2b(hv[r]); cp[r]=f2b(cv[r]); }
      *(us4*)&hb[bb][j0+kq*4] = hp;
      *(us4*)&cb[bb][j0+kq*4] = cp;
    }
  }
  __syncthreads();

  f32x4 uxr[4];
  #pragma unroll
  for (int g=0; g<4; ++g)
    uxr[g] = *(const f32x4*)&ux[(long long)bg*200*1024 + g*256 + jlane];
  float tcur = ts[(long long)bg*200];

  for (int s=0; s<200; ++s){
    // c_s1 pre-act: Wd GEMV over cb
    f32x4 ad = bcs;
    #pragma unroll
    for (int kk=0;kk<8;++kk){
      bf16x8 cf = *(const bf16x8*)&cb[lb][kk*32 + quad*8];
      ad = MFMA(wdA[kk], cf, ad);
    }
    // gates: ux + Wall GEMV over hb
    f32x4 ag[4];
    #pragma unroll
    for (int g=0; g<4; ++g) ag[g] = uxr[g];
    #pragma unroll
    for (int kk=0;kk<8;++kk){
      bf16x8 hf = *(const bf16x8*)&hb[lb][kk*32 + quad*8];
      #pragma unroll
      for (int g=0; g<4; ++g) ag[g] = MFMA(wfA[g][kk], hf, ag[g]);
    }
    // elementwise update (fp32 c carried in regs)
    f32x4 hn; us4 hp, cp;
    #pragma unroll
    for (int r=0;r<4;++r){
      float cs1 = tanhx(ad[r]);
      float cadj = creg[r] + cs1*(tcur - 1.0f);
      float fg = sigm(ag[0][r]);
      float ig = sigm(ag[1][r]);
      float og = sigm(ag[2][r]);
      float cg = sigm(ag[3][r]);
      float cn = fg*cadj + ig*cg;
      float hv = og*tanhx(cn);
      creg[r]=cn; hn[r]=hv;
      hp[r]=f2b(hv); cp[r]=f2b(cn);
    }
    // outputs: lstm0 -> E partial (folded attention dot), lstm1 -> out2
    if (lstm==0){
      float e = hn[0]*wav[0] + hn[1]*wav[1] + hn[2]*wav[2] + hn[3]*wav[3];
      e += __shfl_xor(e, 16, 64);
      e += __shfl_xor(e, 32, 64);
      if (l < 16) atomicAdd(&E[(long long)bg*200 + s], e);
    } else {
      *(us4*)&out2[((long long)bg*200 + s)*256 + jlane] = hp;
    }
    // exchange h,c with the 3 sibling j-WGs
    if (s < 199){
      const int slot = (s+1)&1;
      u64 hv64, cv64;
      __builtin_memcpy(&hv64,&hp,8); __builtin_memcpy(&cv64,&cp,8);
      long long xbase = ((long long)(slot*16 + grp)*16 + lb)*256 + jlane;
      __hip_atomic_store((u64*)&hx[xbase], hv64, __ATOMIC_RELAXED, __HIP_MEMORY_SCOPE_AGENT);
      __hip_atomic_store((u64*)&cx[xbase], cv64, __ATOMIC_RELAXED, __HIP_MEMORY_SCOPE_AGENT);
      __syncthreads();                 // B1: all waves' stores acked at MALL; LDS reads done
      if (tid == 0)
        __hip_atomic_store(&seqw[(slot*16+grp)*4 + jw], s+1, __ATOMIC_RELAXED, __HIP_MEMORY_SCOPE_AGENT);
      // prefetch next step's ux/ts here: latency hides under poll+refill
      #pragma unroll
      for (int g=0; g<4; ++g)
        uxr[g] = *(const f32x4*)&ux[((long long)bg*200 + s+1)*1024 + g*256 + jlane];
      float tnext = ts[(long long)bg*200 + s+1];
      // own chunk: registers -> LDS (compute layout covers own 64 j x 16 b)
      *(us4*)&hb[lb][jlane] = hp;
      *(us4*)&cb[lb][jlane] = cp;
      // sibling chunks: poll writer seq, then relaxed MALL loads
      if (wjw != jw){
        const int* sp = &seqw[(slot*16+grp)*4 + wjw];
        while (__hip_atomic_load(sp, __ATOMIC_RELAXED, __HIP_MEMORY_SCOPE_AGENT) != s+1)
          __builtin_amdgcn_s_sleep(1);
        long long rbase = ((long long)(slot*16 + grp)*16 + bb)*256 + j0;
        u64 hvv[4], cvv[4];
        #pragma unroll
        for (int kq=0;kq<4;++kq){
          hvv[kq] = __hip_atomic_load((const u64*)&hx[rbase + kq*4], __ATOMIC_RELAXED, __HIP_MEMORY_SCOPE_AGENT);
          cvv[kq] = __hip_atomic_load((const u64*)&cx[rbase + kq*4], __ATOMIC_RELAXED, __HIP_MEMORY_SCOPE_AGENT);
        }
        #pragma unroll
        for (int kq=0;kq<4;++kq){
          *(u64*)&hb[bb][j0+kq*4] = hvv[kq];
          *(u64*)&cb[bb][j0+kq*4] = cvv[kq];
        }
      }
      tcur = tnext;
      __syncthreads();                 // B2: LDS h/c(s+1) complete
    }
  }
}

// ---------------- softmax over precomputed E -> alpha ----------------
__global__ __launch_bounds__(256) void k_attn(const float* __restrict__ E, float* __restrict__ alpha){
  __shared__ float buf[256];
  int b = blockIdx.x, tid = threadIdx.x;
  float Ev = (tid < 200) ? E[(long long)b*200 + tid] : -1e30f;
  buf[tid]=Ev; __syncthreads();
  for (int st=128; st>0; st>>=1){ if (tid<st) buf[tid]=fmaxf(buf[tid],buf[tid+st]); __syncthreads(); }
  float mx = buf[0]; __syncthreads();
  float e = (tid<200)? __expf(Ev-mx) : 0.f;
  buf[tid]=e; __syncthreads();
  for (int st=128; st>0; st>>=1){ if (tid<st) buf[tid]+=buf[tid+st]; __syncthreads(); }
  float sm = buf[0];
  if (tid<200) alpha[(long long)b*200+tid] = e/sm;
}

// ---------------- out = ctx @ Wout^T ----------------
__global__ __launch_bounds__(128) void k_out(const float* __restrict__ ctx, const float* __restrict__ Wout,
                                             float* __restrict__ out){
  __shared__ float cs[256];
  int b = blockIdx.x, t = threadIdx.x;
  cs[t] = ctx[b*256+t]; cs[t+128] = ctx[b*256+t+128];
  __syncthreads();
  const float* wr = Wout + (long long)t*256;
  float a0=0,a1=0,a2=0,a3=0;
  for (int j=0;j<256;j+=4){
    f32x4 v = *(const f32x4*)&wr[j];
    a0+=v[0]*cs[j]; a1+=v[1]*cs[j+1]; a2+=v[2]*cs[j+2]; a3+=v[3]*cs[j+3];
  }
  out[(long long)b*128 + t] = (a0+a1)+(a2+a3);
}

extern "C" void kernel_launch(void* const* d_in, const int* in_sizes, int n_in,
                              void* d_out, int out_size, void* d_ws, size_t ws_size,
                              hipStream_t stream)
{
  (void)in_sizes; (void)n_in; (void)out_size; (void)ws_size;
  const float* inputs = (const float*)d_in[0];
  const float* tstamp = (const float*)d_in[1];
  const float* emb    = (const float*)d_in[2];
  const float* Wall1w = (const float*)d_in[3];
  const float* Wall1b = (const float*)d_in[4];
  const float* Uall1w = (const float*)d_in[5];
  const float* Uall1b = (const float*)d_in[6];
  const float* Wd1w   = (const float*)d_in[7];
  const float* Wd1b   = (const float*)d_in[8];
  const float* Wall2w = (const float*)d_in[9];
  const float* Wall2b = (const float*)d_in[10];
  const float* Uall2w = (const float*)d_in[11];
  const float* Uall2b = (const float*)d_in[12];
  const float* Wd2w   = (const float*)d_in[13];
  const float* Wd2b   = (const float*)d_in[14];
  const float* wa     = (const float*)d_in[15];
  const float* Wbw    = (const float*)d_in[16];
  const float* Woutw  = (const float*)d_in[17];
  const float* h01    = (const float*)d_in[18];
  const float* c01    = (const float*)d_in[19];
  const float* h02    = (const float*)d_in[20];
  const float* c02    = (const float*)d_in[21];

  char* ws = (char*)d_ws;
  float* ux1   = (float*)(ws + 0);              // 104857600
  float* ux2   = (float*)(ws + 104857600LL);
  float* embF  = (float*)(ws + 209715200LL);    // 26214400
  u16*   embB  = (u16*)  (ws + 235929600LL);    // 13107200
  char*  scr   =          ws + 249036800LL;     // 72089600 region
  u16*   A0    = (u16*)scr;                     // 72089600 (dead after embed GEMM)
  u16*   out2  = (u16*)  (scr + 0);             // 13107200
  float* alpha = (float*)(scr + 39321600LL);    // 102400
  float* ctx   = (float*)(scr + 39424000LL);    // 131072
  float* E     = (float*)(scr + 39555072LL);    // 102400
  u16*   hx    = (u16*)  (scr + 39657472LL);    // 262144
  u16*   cx    = (u16*)  (scr + 39919616LL);    // 262144
  int*   seqw  = (int*)  (scr + 40181760LL);    // 512
  u16* embT    = (u16*)(ws + 321126400LL);      // 720896
  u16* Wall1B  = (u16*)(ws + 321847296LL);      // 524288
  u16* Wall2B  = (u16*)(ws + 322371584LL);
  u16* Uall1B  = (u16*)(ws + 322895872LL);
  u16* Uall2B  = (u16*)(ws + 323420160LL);
  u16* Wd1B    = (u16*)(ws + 323944448LL);      // 131072
  u16* Wd2B    = (u16*)(ws + 324075520LL);
  u16* WbB     = (u16*)(ws + 324206592LL);
  // total ws: ~324.3 MB (same as passing round-2 layout)

  // 1) all conversions (inputs, emb^T, 7 weights) in one launch
  k_prep<<<37824, 256, 0, stream>>>(inputs, A0, emb, embT,
                                    Wall1w, Wall2w, Uall1w, Uall2w, Wd1w, Wd2w, Wbw,
                                    Wall1B, Wall2B, Uall1B, Uall2B, Wd1B, Wd2B, WbB);
  // 2) embedded = inputs @ emb  (fp32 + bf16 copies)
  k_gemm<1><<<dim3(200,2), 256, 0, stream>>>(A0, embT, 256, 1408, embF, embB,
                                             nullptr, nullptr, nullptr, nullptr,
                                             nullptr, nullptr, nullptr, nullptr);
  // 3) ux1,ux2 = embedded @ Uall{1,2}^T + (Uall_b + Wall_b), one launch
  k_gemm<4><<<dim3(200,16), 256, 0, stream>>>(embB, Uall1B, 1024, 256, ux1, nullptr,
                                              Uall1b, Wall1b,
                                              Uall2B, ux2, Uall2b, Wall2b,
                                              nullptr, nullptr);
  // 4) zero E + ctx (atomic accumulation targets)
  k_init<<<228, 256, 0, stream>>>(E, ctx);
  // 5) both TimeLSTM scans (64 persistent WGs, register-resident weights)
  k_scan<<<64, 256, 0, stream>>>(Wall1B, Wd1B, Wd1b, ux1, h01, c01,
                                 Wall2B, Wd2B, Wd2b, ux2, h02, c02,
                                 tstamp, wa, E, out2, hx, cx, seqw);
  // 6) alpha = softmax(E)
  k_attn<<<128, 256, 0, stream>>>(E, alpha);
  // 7) ctx += sum_s emb * tanh(out2 @ Wb^T) * alpha  (fused, no P buffer)
  k_gemm<5><<<dim3(200,2), 256, 0, stream>>>(out2, WbB, 256, 256, ctx, nullptr,
                                             nullptr, nullptr, nullptr, nullptr,
                                             nullptr, nullptr, embF, alpha);
  // 8) out = ctx @ Wout^T
  k_out<<<128, 128, 0, stream>>>(ctx, Woutw, (float*)d_out);
}